// Round 6
// baseline (307.197 us; speedup 1.0000x reference)
//
#include <hip/hip_runtime.h>
#include <hip/hip_fp16.h>

typedef float f32x4 __attribute__((ext_vector_type(4)));
typedef float f32x16 __attribute__((ext_vector_type(16)));
typedef __bf16 bf16x8 __attribute__((ext_vector_type(8)));
typedef unsigned int u32x4 __attribute__((ext_vector_type(4)));
typedef __attribute__((address_space(3))) const void* lds_cp;

#define BB_ 8
#define TT_ 4096
#define DD_ 1024
#define MM_ (BB_*TT_)   // 32768
#define KK_ DD_         // 1024

#define NCH 64
#define LCH (TT_/NCH)   // 64

static __device__ __forceinline__ unsigned short f2bf_rn(float f) {
  unsigned int u = __float_as_uint(f);
  u += 0x7FFFu + ((u >> 16) & 1u);
  return (unsigned short)(u >> 16);
}

// ---------------- conversion: f32 -> bf16 bits (vectorized) ----------------
__global__ void cvt_f32_bf16(const float4* __restrict__ src,
                             ushort4* __restrict__ dst, int n4) {
  int stride = gridDim.x * blockDim.x;
  for (int i = blockIdx.x * blockDim.x + threadIdx.x; i < n4; i += stride) {
    float4 v = src[i];
    ushort4 o;
    o.x = f2bf_rn(v.x); o.y = f2bf_rn(v.y);
    o.z = f2bf_rn(v.z); o.w = f2bf_rn(v.w);
    dst[i] = o;
  }
}

// ------- GEMM: 256^2, BK=64, 32x32x16 MFMA, asm-pipelined ds_reads --------
__device__ __forceinline__ void gload_lds16(const void* g, void* l) {
  __builtin_amdgcn_global_load_lds(
      (const __attribute__((address_space(1))) void*)g,
      (__attribute__((address_space(3))) void*)l, 16, 0, 0);
}

// Stage a 64-row round (8KB) of A or B for K-tile at half-elem offset kkh.
// Linear LDS dest; global source pre-swizzled (slot s of row r holds global
// 16B-chunk s ^ (r&7)).
#define STA(q, nb_, kkh) gload_lds16(pXa + (q) * 65536 + (kkh), (nb_) + (q) * 8192 + wofs)
#define STB(q, nb_, kkh) gload_lds16(pWb + (q) * 65536 + (kkh), (nb_) + 32768 + (q) * 8192 + wofs)

// inline-asm ds_read_b128: compiler does NOT manage waits for these (we do)
#define DSR(dst, gp) \
  asm volatile("ds_read_b128 %0, %1" : "=&v"(dst) : "v"((lds_cp)(gp)))

// A-fragment quad for quadrant (mh,kh) from buffer bp (4 reads)
#define RD_A(SET, mh, kh, bp) do {                                \
    DSR(SET[0], (bp) + rbA[(mh)*2+0] + ck[(kh)*2+0]);             \
    DSR(SET[1], (bp) + rbA[(mh)*2+0] + ck[(kh)*2+1]);             \
    DSR(SET[2], (bp) + rbA[(mh)*2+1] + ck[(kh)*2+0]);             \
    DSR(SET[3], (bp) + rbA[(mh)*2+1] + ck[(kh)*2+1]);             \
  } while (0)
// B-fragment quad for k-half kh (4 reads)
#define RD_B(SET, kh, bp) do {                                    \
    DSR(SET[0], (bp) + rbB[0] + ck[(kh)*2+0]);                    \
    DSR(SET[1], (bp) + rbB[0] + ck[(kh)*2+1]);                    \
    DSR(SET[2], (bp) + rbB[1] + ck[(kh)*2+0]);                    \
    DSR(SET[3], (bp) + rbB[1] + ck[(kh)*2+1]);                    \
  } while (0)

#define BC(x) __builtin_bit_cast(bf16x8, x)
#define MFMA8(ASET, BSET, mh) do {                                              \
    __builtin_amdgcn_s_setprio(1);                                              \
    acc[(mh)*2+0][0] = __builtin_amdgcn_mfma_f32_32x32x16_bf16(BC(ASET[0]), BC(BSET[0]), acc[(mh)*2+0][0],0,0,0); \
    acc[(mh)*2+0][0] = __builtin_amdgcn_mfma_f32_32x32x16_bf16(BC(ASET[1]), BC(BSET[1]), acc[(mh)*2+0][0],0,0,0); \
    acc[(mh)*2+0][1] = __builtin_amdgcn_mfma_f32_32x32x16_bf16(BC(ASET[0]), BC(BSET[2]), acc[(mh)*2+0][1],0,0,0); \
    acc[(mh)*2+0][1] = __builtin_amdgcn_mfma_f32_32x32x16_bf16(BC(ASET[1]), BC(BSET[3]), acc[(mh)*2+0][1],0,0,0); \
    acc[(mh)*2+1][0] = __builtin_amdgcn_mfma_f32_32x32x16_bf16(BC(ASET[2]), BC(BSET[0]), acc[(mh)*2+1][0],0,0,0); \
    acc[(mh)*2+1][0] = __builtin_amdgcn_mfma_f32_32x32x16_bf16(BC(ASET[3]), BC(BSET[1]), acc[(mh)*2+1][0],0,0,0); \
    acc[(mh)*2+1][1] = __builtin_amdgcn_mfma_f32_32x32x16_bf16(BC(ASET[2]), BC(BSET[2]), acc[(mh)*2+1][1],0,0,0); \
    acc[(mh)*2+1][1] = __builtin_amdgcn_mfma_f32_32x32x16_bf16(BC(ASET[3]), BC(BSET[3]), acc[(mh)*2+1][1],0,0,0); \
    __builtin_amdgcn_s_setprio(0);                                              \
  } while (0)

#define BARSB() do { __builtin_amdgcn_s_barrier();                 \
                     __builtin_amdgcn_sched_barrier(0); } while (0)
#define WAITLK8() do { asm volatile("s_waitcnt lgkmcnt(8)" ::: "memory"); \
                       __builtin_amdgcn_sched_barrier(0); } while (0)
#define WAITLK4() do { asm volatile("s_waitcnt lgkmcnt(4)" ::: "memory"); \
                       __builtin_amdgcn_sched_barrier(0); } while (0)
#define WAITLK0() do { asm volatile("s_waitcnt lgkmcnt(0)" ::: "memory"); \
                       __builtin_amdgcn_sched_barrier(0); } while (0)
#define VM0()   asm volatile("s_waitcnt vmcnt(0)" ::: "memory")

__global__ __launch_bounds__(512, 2) void gemm_fused(
    const unsigned short* __restrict__ Xb,  // [M][K] bf16 bits
    const unsigned short* __restrict__ Wb,  // [2048][K] bf16 bits (Wz;Wh)
    const float* __restrict__ bz, const float* __restrict__ bh,
    __half* __restrict__ Zb, __half* __restrict__ Gb) // each [M][1024]
{
  extern __shared__ __align__(16) char smem[];   // 2 x (A 32KB + B 32KB)
  const int tid  = threadIdx.x;
  const int wave = tid >> 6;
  const int lane = tid & 63;
  const int wm = wave >> 2, wn = wave & 3;       // 2M x 4N waves
  const int ln31 = lane & 31, hi = lane >> 5, sw7 = ln31 & 7;

  // XCD-bijective swizzle (1024 % 8 == 0); N-fastest within each XCD strip.
  int swz = (blockIdx.x & 7) * 128 + (blockIdx.x >> 3);
  const int m0 = (swz >> 3) * 256;
  const int e0 = (swz & 7) * 256;   // concat-N space

  // staging per-thread constants (pre-swizzled global source)
  const int arow = tid >> 3;                         // 0..63 row within round
  const int aslx = ((tid & 7) ^ (arow & 7)) * 8;     // swizzled 16B-chunk, halfs
  const unsigned short* pXa = Xb + (size_t)(m0 + arow) * KK_ + aslx;
  const unsigned short* pWb = Wb + (size_t)(e0 + arow) * KK_ + aslx;
  const int wofs = wave * 1024;                      // wave slice of round (bytes)

  // ds_read per-lane constants (swizzled read side), 32x32x16 fragments:
  // A row = wm*128 + fm*32 + ln31 ; k-chunk = (ks*2 + hi) ^ (row&7)
  int rbA[4], rbB[2], ck[4];
  #pragma unroll
  for (int fm = 0; fm < 4; ++fm) rbA[fm] = (wm * 128 + fm * 32 + ln31) * 128;
  #pragma unroll
  for (int fn = 0; fn < 2; ++fn) rbB[fn] = 32768 + (wn * 64 + fn * 32 + ln31) * 128;
  #pragma unroll
  for (int ks = 0; ks < 4; ++ks) ck[ks] = ((ks * 2 + hi) ^ sw7) * 16;

  f32x16 acc[4][2];
  #pragma unroll
  for (int i = 0; i < 4; i++)
    #pragma unroll
    for (int j = 0; j < 2; j++)
      acc[i][j] = (f32x16)(0.f);
  u32x4 aP[4], aQ[4], bk0[4], bk1[4];   // fragment reg sets (static idx only)

  // prologue: stage K-tile 0 into buf0, drain, publish, read F0 set
  STA(0, smem, 0); STA(1, smem, 0); STA(2, smem, 0); STA(3, smem, 0);
  STB(0, smem, 0); STB(1, smem, 0); STB(2, smem, 0); STB(3, smem, 0);
  VM0();
  __builtin_amdgcn_s_barrier();
  RD_A(aP, 0, 0, smem);                // (mh0,kh0) of tile 0
  RD_B(bk0, 0, smem);                  // k-half 0 B

  #pragma unroll 1
  for (int t = 0; t < 15; ++t) {
    const char* cb = smem + ((t & 1) << 16);
    char* nb = smem + (((t + 1) & 1) << 16);
    const int kn = (t + 1) * 64;                     // half-elem K offset
    // ph0: read (mh1,kh0)->aQ and B k1; stage all 8 rounds of t+1
    BARSB();
    RD_A(aQ, 1, 0, cb); RD_B(bk1, 1, cb);
    STA(0, nb, kn); STA(1, nb, kn); STA(2, nb, kn); STA(3, nb, kn);
    STB(0, nb, kn); STB(1, nb, kn); STB(2, nb, kn); STB(3, nb, kn);
    WAITLK8();                         // drains prev-ph3 reads (aP, bk0)
    MFMA8(aP, bk0, 0);
    // ph1: read (mh0,kh1)->aP
    BARSB();
    RD_A(aP, 0, 1, cb);
    WAITLK4();                         // drains ph0 reads (aQ, bk1)
    MFMA8(aQ, bk0, 1);
    // ph2: read (mh1,kh1)->aQ; drain own staging before ph3 barrier
    BARSB();
    RD_A(aQ, 1, 1, cb);
    WAITLK4();                         // drains ph1 reads (aP)
    MFMA8(aP, bk1, 0);
    VM0();                             // own gloads landed -> publish at ph3 bar
    // ph3: read next tile's (mh0,kh0)->aP and B k0 from nb
    BARSB();
    RD_A(aP, 0, 0, nb); RD_B(bk0, 0, nb);
    WAITLK8();                         // drains ph2 reads (aQ)
    MFMA8(aQ, bk1, 1);
  }
  {                                    // peeled tile 15 (buf1), no staging
    const char* cb = smem + 65536;
    BARSB();
    RD_A(aQ, 1, 0, cb); RD_B(bk1, 1, cb);
    WAITLK8(); MFMA8(aP, bk0, 0);
    BARSB();
    RD_A(aP, 0, 1, cb);
    WAITLK4(); MFMA8(aQ, bk0, 1);
    BARSB();
    RD_A(aQ, 1, 1, cb);
    WAITLK4(); MFMA8(aP, bk1, 0);
    BARSB();
    WAITLK0(); MFMA8(aQ, bk1, 1);
    __builtin_amdgcn_s_barrier();      // all LDS reads done -> smem reusable
  }

  // ---- epilogue: bias + activation, LDS re-layout for coalesced stores ----
  // 32x32 C layout: col = lane&31, row = (r&3) + 8*(r>>2) + 4*hi
  const bool isZ = (e0 < DD_);
  const float* bias = isZ ? bz : bh;
  __half* outp = isZ ? Zb : Gb;
  const int ec0 = (isZ ? e0 : (e0 - DD_)) + wn * 64;

  float bv[2];
  #pragma unroll
  for (int fn = 0; fn < 2; ++fn) bv[fn] = bias[ec0 + fn * 32 + ln31];

  __half* ew = (__half*)(smem + wave * 9216);        // per-wave [64][72] halfs
  const int sub = lane & 7, rowr = lane >> 3;

  #pragma unroll
  for (int p = 0; p < 2; ++p) {                      // two 64-row passes
    #pragma unroll
    for (int f2 = 0; f2 < 2; ++f2) {                 // fm = 2p + f2
      #pragma unroll
      for (int fn = 0; fn < 2; ++fn) {
        #pragma unroll
        for (int r = 0; r < 16; ++r) {
          float val = acc[p * 2 + f2][fn][r] + bv[fn];
          float res;
          if (isZ) {
            res = 1.0f / (1.0f + __expf(-val));      // z = sigmoid(k)
          } else {
            res = (val >= 0.0f) ? (val + 0.5f)       // g(th)
                                : (1.0f / (1.0f + __expf(-val)));
          }
          int rowf = (r & 3) + 8 * (r >> 2) + 4 * hi;
          ew[(f2 * 32 + rowf) * 72 + fn * 32 + ln31] = __float2half(res);
        }
      }
    }
    __builtin_amdgcn_s_barrier();
    #pragma unroll
    for (int q = 0; q < 8; ++q) {                    // coalesced readback+store
      int rl = q * 8 + rowr;
      uint4 v = *reinterpret_cast<const uint4*>(&ew[rl * 72 + sub * 8]);
      size_t rg = (size_t)(m0 + wm * 128 + p * 64 + rl);
      *reinterpret_cast<uint4*>(&outp[rg * DD_ + ec0 + sub * 8]) = v;
    }
    __builtin_amdgcn_s_barrier();
  }
}

// ---------------- scan phase A: per-chunk (P,Q) ----------------
__global__ __launch_bounds__(256) void scan_partial(
    const ushort4* __restrict__ Z, const ushort4* __restrict__ G,
    float4* __restrict__ P, float4* __restrict__ Q) {
  const int d4 = threadIdx.x;   // 0..255 -> 4 dims each
  const int c  = blockIdx.x;    // chunk
  const int b  = blockIdx.y;    // batch
  size_t base = ((size_t)b * TT_ + (size_t)c * LCH) * (DD_ / 4) + d4;
  float p0=1.f,p1=1.f,p2=1.f,p3=1.f, q0=0.f,q1=0.f,q2=0.f,q3=0.f;
  for (int t = 0; t < LCH; ++t) {
    ushort4 uz = Z[base + (size_t)t * (DD_ / 4)];
    ushort4 ug = G[base + (size_t)t * (DD_ / 4)];
    float z, g, a;
    z = __half2float(__ushort_as_half(uz.x)); g = __half2float(__ushort_as_half(ug.x));
    a = 1.f - z; p0 *= a; q0 = fmaf(a, q0, z * g);
    z = __half2float(__ushort_as_half(uz.y)); g = __half2float(__ushort_as_half(ug.y));
    a = 1.f - z; p1 *= a; q1 = fmaf(a, q1, z * g);
    z = __half2float(__ushort_as_half(uz.z)); g = __half2float(__ushort_as_half(ug.z));
    a = 1.f - z; p2 *= a; q2 = fmaf(a, q2, z * g);
    z = __half2float(__ushort_as_half(uz.w)); g = __half2float(__ushort_as_half(ug.w));
    a = 1.f - z; p3 *= a; q3 = fmaf(a, q3, z * g);
  }
  size_t o = ((size_t)b * NCH + c) * (DD_ / 4) + d4;
  P[o] = make_float4(p0, p1, p2, p3);
  Q[o] = make_float4(q0, q1, q2, q3);
}

// ---------------- scan phase B: exclusive scan over chunks ----------------
__global__ __launch_bounds__(256) void scan_combine(
    const float* __restrict__ P, const float* __restrict__ Q,
    float* __restrict__ H) {
  const int d = blockIdx.x * 256 + threadIdx.x;   // gridDim.x = 4 -> d 0..1023
  const int b = blockIdx.y;
  float h = 0.f;
  for (int c = 0; c < NCH; ++c) {
    size_t o = ((size_t)b * NCH + c) * DD_ + d;
    H[o] = h;
    h = fmaf(P[o], h, Q[o]);
  }
}

// ---------------- scan phase C: apply + write output ----------------
__global__ __launch_bounds__(256) void scan_apply(
    const ushort4* __restrict__ Z, const ushort4* __restrict__ G,
    const float4* __restrict__ H, float4* __restrict__ out) {
  const int d4 = threadIdx.x;
  const int c  = blockIdx.x;
  const int b  = blockIdx.y;
  float4 h = H[((size_t)b * NCH + c) * (DD_ / 4) + d4];
  size_t base = ((size_t)b * TT_ + (size_t)c * LCH) * (DD_ / 4) + d4;
  for (int t = 0; t < LCH; ++t) {
    ushort4 uz = Z[base + (size_t)t * (DD_ / 4)];
    ushort4 ug = G[base + (size_t)t * (DD_ / 4)];
    float z, g, a;
    z = __half2float(__ushort_as_half(uz.x)); g = __half2float(__ushort_as_half(ug.x));
    a = 1.f - z; h.x = fmaf(a, h.x, z * g);
    z = __half2float(__ushort_as_half(uz.y)); g = __half2float(__ushort_as_half(ug.y));
    a = 1.f - z; h.y = fmaf(a, h.y, z * g);
    z = __half2float(__ushort_as_half(uz.z)); g = __half2float(__ushort_as_half(ug.z));
    a = 1.f - z; h.z = fmaf(a, h.z, z * g);
    z = __half2float(__ushort_as_half(uz.w)); g = __half2float(__ushort_as_half(ug.w));
    a = 1.f - z; h.w = fmaf(a, h.w, z * g);
    out[base + (size_t)t * (DD_ / 4)] = h;
  }
}

extern "C" void kernel_launch(void* const* d_in, const int* in_sizes, int n_in,
                              void* d_out, int out_size, void* d_ws, size_t ws_size,
                              hipStream_t stream) {
  const float* X  = (const float*)d_in[0];  // [8,4096,1024]
  const float* Wz = (const float*)d_in[1];  // [1024,1024]
  const float* bz = (const float*)d_in[2];
  const float* Wh = (const float*)d_in[3];
  const float* bh = (const float*)d_in[4];
  float* out = (float*)d_out;

  const size_t szXb = (size_t)MM_ * DD_ * 2;      // 64 MiB  bf16 X
  const size_t szWb = (size_t)2 * DD_ * DD_ * 2;  //  4 MiB  bf16 (Wz;Wh)
  const size_t szZ  = (size_t)MM_ * DD_ * 2;      // 64 MiB  fp16 each
  const size_t szPQ = (size_t)BB_ * NCH * DD_ * 4;//  2 MiB  each

  char* ws = (char*)d_ws;
  unsigned short *Xb, *Wb;
  __half *Zb, *Gb;
  const size_t needA = szXb + szWb + 2 * szZ + 3 * szPQ;
  if (ws_size >= needA) {
    Xb = (unsigned short*)ws;              ws += szXb;
    Wb = (unsigned short*)ws;              ws += szWb;
  } else {
    // fallback: stage X/W inside d_out (dead after GEMM), scan state in ws
    Xb = (unsigned short*)d_out;
    Wb = (unsigned short*)((char*)d_out + szXb);
  }
  Zb = (__half*)ws;  ws += szZ;
  Gb = (__half*)ws;  ws += szZ;
  float* P = (float*)ws;  ws += szPQ;
  float* Q = (float*)ws;  ws += szPQ;
  float* H = (float*)ws;

  // 1) convert inputs to bf16
  cvt_f32_bf16<<<2048, 256, 0, stream>>>((const float4*)X, (ushort4*)Xb,
                                         (int)((size_t)MM_ * DD_ / 4));
  cvt_f32_bf16<<<512, 256, 0, stream>>>((const float4*)Wz, (ushort4*)Wb,
                                        DD_ * DD_ / 4);
  cvt_f32_bf16<<<512, 256, 0, stream>>>((const float4*)Wh,
                                        (ushort4*)(Wb + (size_t)DD_ * DD_),
                                        DD_ * DD_ / 4);
  // 2) fused GEMM -> z, g  (M=32768, N=2048 concat, K=1024), 128KB dyn-LDS
  gemm_fused<<<(MM_ / 256) * ((2 * DD_) / 256), 512, 131072, stream>>>(
      Xb, Wb, bz, bh, Zb, Gb);

  // 3) chunked linear scan over T
  scan_partial<<<dim3(NCH, BB_), 256, 0, stream>>>((const ushort4*)Zb, (const ushort4*)Gb,
                                                   (float4*)P, (float4*)Q);
  scan_combine<<<dim3(4, BB_), 256, 0, stream>>>(P, Q, H);
  scan_apply<<<dim3(NCH, BB_), 256, 0, stream>>>((const ushort4*)Zb, (const ushort4*)Gb,
                                                 (const float4*)H, (float4*)out);
}

// Round 7
// 289.316 us; speedup vs baseline: 1.0618x; 1.0618x over previous
//
#include <hip/hip_runtime.h>
#include <hip/hip_fp16.h>

typedef float f32x4 __attribute__((ext_vector_type(4)));
typedef __bf16 bf16x8 __attribute__((ext_vector_type(8)));

#define BB_ 8
#define TT_ 4096
#define DD_ 1024
#define MM_ (BB_*TT_)   // 32768
#define KK_ DD_         // 1024

#define NCH 64
#define LCH (TT_/NCH)   // 64

static __device__ __forceinline__ unsigned short f2bf_rn(float f) {
  unsigned int u = __float_as_uint(f);
  u += 0x7FFFu + ((u >> 16) & 1u);
  return (unsigned short)(u >> 16);
}

// ---------------- conversion: f32 -> bf16 bits (vectorized) ----------------
__global__ void cvt_f32_bf16(const float4* __restrict__ src,
                             ushort4* __restrict__ dst, int n4) {
  int stride = gridDim.x * blockDim.x;
  for (int i = blockIdx.x * blockDim.x + threadIdx.x; i < n4; i += stride) {
    float4 v = src[i];
    ushort4 o;
    o.x = f2bf_rn(v.x); o.y = f2bf_rn(v.y);
    o.z = f2bf_rn(v.z); o.w = f2bf_rn(v.w);
    dst[i] = o;
  }
}

// ---- GEMM: 256^2 tile, K=32 half-tiles, 4 LDS bufs, deep counted vmcnt ----
__device__ __forceinline__ void gload_lds16(const void* g, void* l) {
  __builtin_amdgcn_global_load_lds(
      (const __attribute__((address_space(1))) void*)g,
      (__attribute__((address_space(3))) void*)l, 16, 0, 0);
}

// Half-tile buffer (32KB): A [256 rows][32 halfs] @0, B same @16384.
// Round q covers rows q*128..q*128+127. Source pre-swizzled: LDS chunk-slot s
// of row r holds global 16B-chunk (s ^ (r&3)); read side applies same XOR.
#define STA2(q, buf_, kkh) gload_lds16(pXa + (size_t)(q) * 131072 + (kkh), (buf_) + (q) * 8192 + wofs)
#define STB2(q, buf_, kkh) gload_lds16(pWb + (size_t)(q) * 131072 + (kkh), (buf_) + 16384 + (q) * 8192 + wofs)

// One phase (mh = M-half of wave tile). ds_reads (C++; compiler-managed
// waits) -> stage 2 rounds -> [counted vmcnt] -> barrier -> lgkm0 ->
// setprio(1) 16xMFMA setprio(0) -> barrier.
#define PH(buf_, mh, STAGEOPS, WAITOPS) do {                                \
    const char* Ab_ = (const char*)(buf_);                                  \
    bf16x8 af_[4];                                                          \
    _Pragma("unroll")                                                       \
    for (int ii = 0; ii < 4; ++ii)                                          \
      af_[ii] = *reinterpret_cast<const bf16x8*>(                           \
          Ab_ + rAb + (mh) * 4096 + ii * 1024);                             \
    if ((mh) == 0) {                                                        \
      _Pragma("unroll")                                                     \
      for (int j = 0; j < 4; ++j)                                           \
        bfv[j] = *reinterpret_cast<const bf16x8*>(Ab_ + rBb + j * 1024);    \
    }                                                                       \
    STAGEOPS;                                                               \
    WAITOPS;                                                                \
    __builtin_amdgcn_s_barrier();                                           \
    asm volatile("s_waitcnt lgkmcnt(0)" ::: "memory");                      \
    __builtin_amdgcn_sched_barrier(0);                                      \
    __builtin_amdgcn_s_setprio(1);                                          \
    _Pragma("unroll")                                                       \
    for (int ii = 0; ii < 4; ++ii)                                          \
      _Pragma("unroll")                                                     \
      for (int j = 0; j < 4; ++j)                                           \
        acc[(mh) * 4 + ii][j] = __builtin_amdgcn_mfma_f32_16x16x32_bf16(    \
            af_[ii], bfv[j], acc[(mh) * 4 + ii][j], 0, 0, 0);               \
    __builtin_amdgcn_s_setprio(0);                                          \
    asm volatile("" ::: "memory");                                          \
    __builtin_amdgcn_s_barrier();                                           \
  } while (0)

#define VMW(n) asm volatile("s_waitcnt vmcnt(" #n ")" ::: "memory")

__global__ __launch_bounds__(512, 2) void gemm_fused(
    const unsigned short* __restrict__ Xb,  // [M][K] bf16 bits
    const unsigned short* __restrict__ Wb,  // [2048][K] bf16 bits (Wz;Wh)
    const float* __restrict__ bz, const float* __restrict__ bh,
    __half* __restrict__ Zb, __half* __restrict__ Gb) // each [M][1024]
{
  extern __shared__ __align__(16) char smem[];   // 4 x 32KB half-tile bufs
  const int tid  = threadIdx.x;
  const int wave = tid >> 6;
  const int lane = tid & 63;
  const int wm = wave >> 2, wn = wave & 3;       // 2M x 4N waves
  const int fr = lane & 15, kg = lane >> 4;

  // XCD-bijective swizzle (1024 % 8 == 0); N-fastest within each XCD strip.
  int swz = (blockIdx.x & 7) * 128 + (blockIdx.x >> 3);
  const int m0 = (swz >> 3) * 256;
  const int e0 = (swz & 7) * 256;   // concat-N space

  // staging per-thread constants (pre-swizzled global source)
  const int arow2 = tid >> 2;                        // 0..127 row within round
  const int ac = ((tid & 3) ^ (arow2 & 3)) * 8;      // swizzled chunk, halfs
  const unsigned short* pXa = Xb + (size_t)(m0 + arow2) * KK_ + ac;
  const unsigned short* pWb = Wb + (size_t)(e0 + arow2) * KK_ + ac;
  const int wofs = wave * 1024;                      // wave slice (bytes)

  // ds_read per-lane constants (swizzled read side)
  const int cksw = ((kg ^ (fr & 3)) << 4);           // chunk byte in 64B row
  const int rAb = (wm * 128 + fr) * 64 + cksw;       // A base byte
  const int rBb = 16384 + (wn * 64 + fr) * 64 + cksw;// B base byte

  f32x4 acc[8][4];
  #pragma unroll
  for (int i = 0; i < 8; i++)
    #pragma unroll
    for (int j = 0; j < 4; j++)
      acc[i][j] = (f32x4){0.f, 0.f, 0.f, 0.f};
  bf16x8 bfv[4];

  // prologue: stage half-tiles 0,1,2 into bufs 0,1,2 (12 loads), drain hp0
  STA2(0, smem, 0);           STA2(1, smem, 0);
  STB2(0, smem, 0);           STB2(1, smem, 0);
  STA2(0, smem + 32768, 32);  STA2(1, smem + 32768, 32);
  STB2(0, smem + 32768, 32);  STB2(1, smem + 32768, 32);
  STA2(0, smem + 65536, 64);  STA2(1, smem + 65536, 64);
  STB2(0, smem + 65536, 64);  STB2(1, smem + 65536, 64);
  VMW(8);                                            // hp0's 4 landed
  __builtin_amdgcn_s_barrier();

  // main loop: hp = 0..28, stage hp+3; 32 half-tiles total (K=1024)
  #pragma unroll 1
  for (int t = 0; t < 29; ++t) {
    const char* cb = smem + ((t & 3) << 15);
    char* nb = smem + (((t + 3) & 3) << 15);
    const int kn = (t + 3) * 32;                     // half-elem K offset
    // ph0: reads need ALL of hp's 4 loads (drained at hp-1 ph1); stage A
    PH(cb, 0, {STA2(0, nb, kn); STA2(1, nb, kn);}, );
    // ph1: stage B; drain hp+1's loads (age 3 phases): newer = hp+2(4)+hp+3(4)
    PH(cb, 1, {STB2(0, nb, kn); STB2(1, nb, kn);}, VMW(8));
  }
  {                                                  // peeled hp 29,30,31
    const char* b1 = smem + 32768;
    const char* b2 = smem + 65536;
    const char* b3 = smem + 98304;
    PH(b1, 0, {}, );
    PH(b1, 1, {}, VMW(4));                           // drain hp30 (newer: hp31)
    PH(b2, 0, {}, );
    PH(b2, 1, {}, VMW(0));                           // drain hp31
    PH(b3, 0, {}, );
    PH(b3, 1, {}, );
  }
  // last PH's trailing barrier: all LDS reads done -> smem reusable

  // ---- epilogue: bias + activation, LDS re-layout for coalesced stores ----
  const bool isZ = (e0 < DD_);
  const float* bias = isZ ? bz : bh;
  __half* outp = isZ ? Zb : Gb;
  const int ec0 = (isZ ? e0 : (e0 - DD_)) + wn * 64;

  float bv[4];
  #pragma unroll
  for (int j = 0; j < 4; j++) bv[j] = bias[ec0 + j * 16 + fr];

  __half* ew = (__half*)(smem + wave * 9216);        // per-wave [64][72] halfs
  const int sub = lane & 7, rowr = lane >> 3;

  #pragma unroll
  for (int p = 0; p < 2; ++p) {                      // two 64-row passes
    #pragma unroll
    for (int ii = 0; ii < 4; ++ii) {
      #pragma unroll
      for (int j = 0; j < 4; ++j) {
        #pragma unroll
        for (int r = 0; r < 4; ++r) {
          float val = acc[p * 4 + ii][j][r] + bv[j];
          float res;
          if (isZ) {
            res = 1.0f / (1.0f + __expf(-val));      // z = sigmoid(k)
          } else {
            res = (val >= 0.0f) ? (val + 0.5f)       // g(th)
                                : (1.0f / (1.0f + __expf(-val)));
          }
          ew[(ii * 16 + kg * 4 + r) * 72 + j * 16 + fr] = __float2half(res);
        }
      }
    }
    #pragma unroll
    for (int q = 0; q < 8; ++q) {                    // coalesced readback+store
      int rl = q * 8 + rowr;
      uint4 v = *reinterpret_cast<const uint4*>(&ew[rl * 72 + sub * 8]);
      size_t rg = (size_t)(m0 + wm * 128 + p * 64 + rl);
      *reinterpret_cast<uint4*>(&outp[rg * DD_ + ec0 + sub * 8]) = v;
    }
  }
}

// ---------------- scan phase A: per-chunk (P,Q) ----------------
__global__ __launch_bounds__(256) void scan_partial(
    const ushort4* __restrict__ Z, const ushort4* __restrict__ G,
    float4* __restrict__ P, float4* __restrict__ Q) {
  const int d4 = threadIdx.x;   // 0..255 -> 4 dims each
  const int c  = blockIdx.x;    // chunk
  const int b  = blockIdx.y;    // batch
  size_t base = ((size_t)b * TT_ + (size_t)c * LCH) * (DD_ / 4) + d4;
  float p0=1.f,p1=1.f,p2=1.f,p3=1.f, q0=0.f,q1=0.f,q2=0.f,q3=0.f;
  for (int t = 0; t < LCH; ++t) {
    ushort4 uz = Z[base + (size_t)t * (DD_ / 4)];
    ushort4 ug = G[base + (size_t)t * (DD_ / 4)];
    float z, g, a;
    z = __half2float(__ushort_as_half(uz.x)); g = __half2float(__ushort_as_half(ug.x));
    a = 1.f - z; p0 *= a; q0 = fmaf(a, q0, z * g);
    z = __half2float(__ushort_as_half(uz.y)); g = __half2float(__ushort_as_half(ug.y));
    a = 1.f - z; p1 *= a; q1 = fmaf(a, q1, z * g);
    z = __half2float(__ushort_as_half(uz.z)); g = __half2float(__ushort_as_half(ug.z));
    a = 1.f - z; p2 *= a; q2 = fmaf(a, q2, z * g);
    z = __half2float(__ushort_as_half(uz.w)); g = __half2float(__ushort_as_half(ug.w));
    a = 1.f - z; p3 *= a; q3 = fmaf(a, q3, z * g);
  }
  size_t o = ((size_t)b * NCH + c) * (DD_ / 4) + d4;
  P[o] = make_float4(p0, p1, p2, p3);
  Q[o] = make_float4(q0, q1, q2, q3);
}

// ---------------- scan phase B: exclusive scan over chunks ----------------
__global__ __launch_bounds__(256) void scan_combine(
    const float* __restrict__ P, const float* __restrict__ Q,
    float* __restrict__ H) {
  const int d = blockIdx.x * 256 + threadIdx.x;   // gridDim.x = 4 -> d 0..1023
  const int b = blockIdx.y;
  float h = 0.f;
  for (int c = 0; c < NCH; ++c) {
    size_t o = ((size_t)b * NCH + c) * DD_ + d;
    H[o] = h;
    h = fmaf(P[o], h, Q[o]);
  }
}

// ---------------- scan phase C: apply + write output ----------------
__global__ __launch_bounds__(256) void scan_apply(
    const ushort4* __restrict__ Z, const ushort4* __restrict__ G,
    const float4* __restrict__ H, float4* __restrict__ out) {
  const int d4 = threadIdx.x;
  const int c  = blockIdx.x;
  const int b  = blockIdx.y;
  float4 h = H[((size_t)b * NCH + c) * (DD_ / 4) + d4];
  size_t base = ((size_t)b * TT_ + (size_t)c * LCH) * (DD_ / 4) + d4;
  for (int t = 0; t < LCH; ++t) {
    ushort4 uz = Z[base + (size_t)t * (DD_ / 4)];
    ushort4 ug = G[base + (size_t)t * (DD_ / 4)];
    float z, g, a;
    z = __half2float(__ushort_as_half(uz.x)); g = __half2float(__ushort_as_half(ug.x));
    a = 1.f - z; h.x = fmaf(a, h.x, z * g);
    z = __half2float(__ushort_as_half(uz.y)); g = __half2float(__ushort_as_half(ug.y));
    a = 1.f - z; h.y = fmaf(a, h.y, z * g);
    z = __half2float(__ushort_as_half(uz.z)); g = __half2float(__ushort_as_half(ug.z));
    a = 1.f - z; h.z = fmaf(a, h.z, z * g);
    z = __half2float(__ushort_as_half(uz.w)); g = __half2float(__ushort_as_half(ug.w));
    a = 1.f - z; h.w = fmaf(a, h.w, z * g);
    out[base + (size_t)t * (DD_ / 4)] = h;
  }
}

extern "C" void kernel_launch(void* const* d_in, const int* in_sizes, int n_in,
                              void* d_out, int out_size, void* d_ws, size_t ws_size,
                              hipStream_t stream) {
  const float* X  = (const float*)d_in[0];  // [8,4096,1024]
  const float* Wz = (const float*)d_in[1];  // [1024,1024]
  const float* bz = (const float*)d_in[2];
  const float* Wh = (const float*)d_in[3];
  const float* bh = (const float*)d_in[4];
  float* out = (float*)d_out;

  const size_t szXb = (size_t)MM_ * DD_ * 2;      // 64 MiB  bf16 X
  const size_t szWb = (size_t)2 * DD_ * DD_ * 2;  //  4 MiB  bf16 (Wz;Wh)
  const size_t szZ  = (size_t)MM_ * DD_ * 2;      // 64 MiB  fp16 each
  const size_t szPQ = (size_t)BB_ * NCH * DD_ * 4;//  2 MiB  each

  char* ws = (char*)d_ws;
  unsigned short *Xb, *Wb;
  __half *Zb, *Gb;
  const size_t needA = szXb + szWb + 2 * szZ + 3 * szPQ;
  if (ws_size >= needA) {
    Xb = (unsigned short*)ws;              ws += szXb;
    Wb = (unsigned short*)ws;              ws += szWb;
  } else {
    // fallback: stage X/W inside d_out (dead after GEMM), scan state in ws
    Xb = (unsigned short*)d_out;
    Wb = (unsigned short*)((char*)d_out + szXb);
  }
  Zb = (__half*)ws;  ws += szZ;
  Gb = (__half*)ws;  ws += szZ;
  float* P = (float*)ws;  ws += szPQ;
  float* Q = (float*)ws;  ws += szPQ;
  float* H = (float*)ws;

  // 1) convert inputs to bf16
  cvt_f32_bf16<<<2048, 256, 0, stream>>>((const float4*)X, (ushort4*)Xb,
                                         (int)((size_t)MM_ * DD_ / 4));
  cvt_f32_bf16<<<512, 256, 0, stream>>>((const float4*)Wz, (ushort4*)Wb,
                                        DD_ * DD_ / 4);
  cvt_f32_bf16<<<512, 256, 0, stream>>>((const float4*)Wh,
                                        (ushort4*)(Wb + (size_t)DD_ * DD_),
                                        DD_ * DD_ / 4);
  // 2) fused GEMM -> z, g  (M=32768, N=2048 concat, K=1024), 128KB dyn-LDS
  gemm_fused<<<(MM_ / 256) * ((2 * DD_) / 256), 512, 131072, stream>>>(
      Xb, Wb, bz, bh, Zb, Gb);

  // 3) chunked linear scan over T
  scan_partial<<<dim3(NCH, BB_), 256, 0, stream>>>((const ushort4*)Zb, (const ushort4*)Gb,
                                                   (float4*)P, (float4*)Q);
  scan_combine<<<dim3(4, BB_), 256, 0, stream>>>(P, Q, H);
  scan_apply<<<dim3(NCH, BB_), 256, 0, stream>>>((const ushort4*)Zb, (const ushort4*)Gb,
                                                 (const float4*)H, (float4*)out);
}